// Round 10
// baseline (69568.994 us; speedup 1.0000x reference)
//
#include <hip/hip_runtime.h>
#include <hip/hip_bf16.h>
#include <math.h>

#define NEGF (-1000000000.0f)

constexpr int Bc = 8;
constexpr int Sc = 64;
constexpr int Hc = 512;
constexpr int Tc = 17;
constexpr int TRIc = Sc*(Sc+1)/2;     // 2080
constexpr int PTN  = Bc*Tc*Sc*Sc;     // elements per pt part

typedef __bf16 bf16x8 __attribute__((ext_vector_type(8)));
typedef float  f32x4  __attribute__((ext_vector_type(4)));

__device__ __forceinline__ int tri_idx(int i, int j){
  return i*Sc - (i*(i-1))/2 + (j - i);
}

// (i,j) position + activity for (pass, row r, step k, length L)
__device__ __forceinline__ void posmap(int pass, int r, int k, int L,
                                       int& i, int& j, bool& act){
  if      (pass == 0){ act = (r < L - k);            i = r;     j = L - 1 - k; }
  else if (pass == 1){ act = (r < L - k);            i = r;     j = r + k;     }
  else if (pass == 2){ act = (r >= k) && (r < L);    i = r - k; j = r;         }
  else               { act = (r >= k) && (r < L);    i = k;     j = r;         }
  if (!act){ i = 0; j = 0; }
}

// masked pt value; pt split in 4 parts of PTN elements
__device__ __forceinline__ float pt_val(const float* __restrict__ pt_acc,
                                        const float* __restrict__ btv,
                                        int b, int t, int i, int j, int L){
  const bool masked = (i > j) || (j >= L) ||
                      (t < Tc-1 && i == j) || (t == Tc-1 && i < j);
  if (masked) return NEGF;
  const size_t idx = (((size_t)b*Tc + t)*Sc + i)*Sc + j;
  return pt_acc[idx] + pt_acc[PTN + idx] + pt_acc[2*PTN + idx]
       + pt_acc[3*PTN + idx] + btv[t];
}

// ---------------------------------------------------------------------------
__global__ __launch_bounds__(256) void k_cvt(const float* __restrict__ s,
                                             __hip_bfloat16* __restrict__ d, int n4){
  int i = blockIdx.x*256 + threadIdx.x;
  if (i >= n4) return;
  float4 v = reinterpret_cast<const float4*>(s)[i];
  union { __hip_bfloat16 h[4]; ushort4 u; } p;
  p.h[0] = __float2bfloat16(v.x); p.h[1] = __float2bfloat16(v.y);
  p.h[2] = __float2bfloat16(v.z); p.h[3] = __float2bfloat16(v.w);
  reinterpret_cast<ushort4*>(d)[i] = p.u;
}

// ---------------------------------------------------------------------------
// Weight prepack: Wp[wset][us(32)][row(64)][k(1024)] bf16
// ---------------------------------------------------------------------------
__global__ __launch_bounds__(256) void k_pack(
    const float* __restrict__ Whh_f, const float* __restrict__ Wih_f,
    const float* __restrict__ Whh_b, const float* __restrict__ Wih_b,
    __hip_bfloat16* __restrict__ Wp)
{
  int idx = blockIdx.x*256 + threadIdx.x;   // 1,048,576 quads
  int k4  = idx & 255;
  int row = (idx >> 8) & 63;
  int us  = (idx >> 14) & 31;
  int ws  = idx >> 19;
  int g = row >> 4, uu = row & 15;
  int srow = g*512 + us*16 + uu;
  int k = k4*4;
  const float* src;
  if (ws == 0) src = (k < 512) ? Whh_f : Wih_f;
  else         src = (k < 512) ? Whh_b : Wih_b;
  float4 v = *reinterpret_cast<const float4*>(src + (size_t)srow*512 + (k & 511));
  union { __hip_bfloat16 h[4]; ushort4 u; } p;
  p.h[0] = __float2bfloat16(v.x); p.h[1] = __float2bfloat16(v.y);
  p.h[2] = __float2bfloat16(v.z); p.h[3] = __float2bfloat16(v.w);
  *reinterpret_cast<ushort4*>(Wp + (size_t)idx*4) = p.u;
}

// ---------------------------------------------------------------------------
// Persistent 4-pass LSTM, wave-decoupled sync + x-GEMM prefetch.
// 256 blocks x 512 threads, 1 block/CU. grp = bid&7 (XCD-pinned: pp=grp>>2,
// bq=grp&3), us = bid>>3. Per-pass-half flag sync (128 waves), NO barriers
// in the loop. Per step per wave: [acquire(k-1); project(k-1); hGEMM(k) onto
// prefetched x-gates; cell; H write; release(k); xGEMM(k+1)].
// ---------------------------------------------------------------------------
__global__ __launch_bounds__(512) void k_persist3(
    const __hip_bfloat16* __restrict__ Wp,
    const float* __restrict__ bih_f, const float* __restrict__ bhh_f,
    const float* __restrict__ bih_b, const float* __restrict__ bhh_b,
    const __hip_bfloat16* __restrict__ svb, const float* __restrict__ Wt,
    const int* __restrict__ lens,
    __hip_bfloat16* __restrict__ H,
    float* __restrict__ pt_acc, int* __restrict__ cnt)
{
  const int bid = blockIdx.x;
  const int grp = bid & 7;          // XCD-aligned group
  const int us  = bid >> 3;         // 0..31
  const int pp  = grp >> 2;         // weight set (one per XCD)
  const int bq  = grp & 3;          // batch pair (one per XCD)
  const int L0 = lens[bq*2], L1 = lens[bq*2+1];

  const float* b1 = pp ? bih_b : bih_f;
  const float* b2 = pp ? bhh_b : bhh_f;

  const int t = threadIdx.x, lane = t & 63, wv = t >> 6;
  const int c15 = lane & 15, qq = lane >> 4;
  const int ph = wv >> 2;           // pass half
  const int mq = wv & 3;            // row quarter
  const int pass = pp ? (ph ? 2 : 1) : (ph ? 3 : 0);
  const int b_loc = mq >> 1;
  const int b  = bq*2 + b_loc;
  const int L  = b_loc ? L1 : L0;
  const int rb0 = (mq & 1)*32;      // within-batch row base (+mt*16)

  __shared__ ushort Wlds[65536];    // 128 KiB: 64 rows x 2048 B, XOR-swizzled

  // ---- one-time W stage (swizzle byte-addr ^ (row&7)<<4) ----
  {
    const __hip_bfloat16* Wpb = Wp + (((size_t)pp*32 + us)*64)*1024;
    const int row = t >> 3, c8 = t & 7;
    const int swz = (row & 7) << 4;
    #pragma unroll
    for (int q=0; q<16; ++q){
      int4 v = *reinterpret_cast<const int4*>(Wpb + (size_t)row*1024 + c8*128 + q*8);
      *reinterpret_cast<int4*>((char*)Wlds + ((row*2048 + c8*256 + q*16) ^ swz)) = v;
    }
  }

  const int u = us*16 + c15;
  const float bsI = b1[u]        + b2[u];
  const float bsF = b1[512 + u]  + b2[512 + u];
  const float bsG = b1[1024 + u] + b2[1024 + u];
  const float bsO = b1[1536 + u] + b2[1536 + u];
  const int lswz = (c15 & 7) << 4;

  // projection: own-pass-half rows; pidx = us*4 + mq in 0..127 (bijective)
  const int pidx = us*4 + mq;
  const int bp   = bq*2 + (pidx >> 6);
  const int rp   = pidx & 63;
  const int Lp   = (pidx >> 6) ? L1 : L0;
  const int off_wtp = (pass==0 || pass==2) ? 512 : 0;
  int* flag = cnt + ((size_t)grp*2 + ph)*64;

  float creg[2][4];
  #pragma unroll
  for (int mt=0; mt<2; ++mt)
    #pragma unroll
    for (int e=0; e<4; ++e) creg[mt][e] = 0.f;

  __syncthreads();                  // Wlds ready (only barrier in kernel)

  // ---- x-GEMM for step s into xn (chunks 8..15 of K) ----
  auto xgemm = [&](int s, f32x4 (&xn)[2][4]){
    #pragma unroll
    for (int mt=0; mt<2; ++mt)
      #pragma unroll
      for (int g=0; g<4; ++g) xn[mt][g] = f32x4{0.f,0.f,0.f,0.f};
    if (s >= 64) return;
    #pragma unroll
    for (int mt=0; mt<2; ++mt){
      const int rbase = rb0 + mt*16;
      const bool act_tile = (pass < 2) ? (rbase < L - s)
                                       : (rbase + 15 >= s && rbase < L);
      if (!act_tile) continue;
      const int r = rbase + c15;
      int i, j; bool a_;
      posmap(pass, r, s, L, i, j, a_);
      const __hip_bfloat16* xp = svb + ((size_t)b*TRIc + tri_idx(i, j))*512;
      #pragma unroll
      for (int c=8; c<16; ++c){
        const int o = (c-8)*64 + qq*8;
        bf16x8 a0 = *reinterpret_cast<const bf16x8*>(xp + o);
        bf16x8 a1 = *reinterpret_cast<const bf16x8*>(xp + o + 32);
        #pragma unroll
        for (int g=0; g<4; ++g){
          const int ad0 = (((g*16 + c15)*2048) + (c*2+0)*64 + qq*16) ^ lswz;
          const int ad1 = (((g*16 + c15)*2048) + (c*2+1)*64 + qq*16) ^ lswz;
          xn[mt][g] = __builtin_amdgcn_mfma_f32_16x16x32_bf16(
              a0, *reinterpret_cast<const bf16x8*>((const char*)Wlds + ad0), xn[mt][g], 0,0,0);
          xn[mt][g] = __builtin_amdgcn_mfma_f32_16x16x32_bf16(
              a1, *reinterpret_cast<const bf16x8*>((const char*)Wlds + ad1), xn[mt][g], 0,0,0);
        }
      }
    }
  };

  // ---- projection of one row for step t_ (H parity (t_&1)^1) ----
  auto project = [&](int t_){
    if (t_ >= Lp) return;
    int pi, pj; bool pact;
    posmap(pass, rp, t_, Lp, pi, pj, pact);
    if (!pact) return;
    const __hip_bfloat16* hrow =
        H + (((size_t)((t_ & 1) ^ 1)*4 + pass)*512 + bp*64 + rp)*512;
    bf16x8 hv8 = *reinterpret_cast<const bf16x8*>(hrow + lane*8);
    float hf[8];
    #pragma unroll
    for (int e=0; e<8; ++e) hf[e] = (float)hv8[e];
    float part[Tc];
    #pragma unroll
    for (int tt=0; tt<Tc; ++tt){
      const float* w = Wt + (size_t)tt*1024 + off_wtp + lane*8;
      float4 w0 = *reinterpret_cast<const float4*>(w);
      float4 w1 = *reinterpret_cast<const float4*>(w + 4);
      part[tt] = hf[0]*w0.x + hf[1]*w0.y + hf[2]*w0.z + hf[3]*w0.w
               + hf[4]*w1.x + hf[5]*w1.y + hf[6]*w1.z + hf[7]*w1.w;
    }
    float* ptp = pt_acc + (size_t)(us & 3)*PTN;
    #pragma unroll
    for (int tt=0; tt<Tc; ++tt){
      float s = part[tt];
      s += __shfl_xor(s, 1);  s += __shfl_xor(s, 2);  s += __shfl_xor(s, 4);
      s += __shfl_xor(s, 8);  s += __shfl_xor(s, 16); s += __shfl_xor(s, 32);
      if (lane == tt)
        atomicAdd(&ptp[(((size_t)bp*Tc + tt)*Sc + pi)*Sc + pj], s);
    }
  };

  f32x4 xc[2][4], xn[2][4];
  xgemm(0, xc);                     // prologue

  for (int k=0; k<64; ++k){
    // ---- acquire H(k-1) + project step k-1 ----
    if (k > 0){
      while (__hip_atomic_load(&flag[k-1], __ATOMIC_ACQUIRE,
                               __HIP_MEMORY_SCOPE_AGENT) < 128)
        __builtin_amdgcn_s_sleep(2);
      project(k-1);
    }

    // ---- h-GEMM(k) onto xc + cell + H write ----
    bool act_t[2];
    #pragma unroll
    for (int mt=0; mt<2; ++mt){
      const int rbase = rb0 + mt*16;
      act_t[mt] = (pass < 2) ? (rbase < L - k)
                             : (rbase + 15 >= k && rbase < L);
    }
    if (act_t[0] || act_t[1]){
      if (k > 0){                   // h(k-1)=0 at k=0
        const int cur = k & 1;
        #pragma unroll
        for (int mt=0; mt<2; ++mt){
          if (!act_t[mt]) continue;
          const int r = rb0 + mt*16 + c15;
          const __hip_bfloat16* hp =
              H + (((size_t)cur*4 + pass)*512 + b*64 + r)*512;
          #pragma unroll
          for (int c=0; c<8; ++c){
            const int o = c*64 + qq*8;
            bf16x8 a0 = *reinterpret_cast<const bf16x8*>(hp + o);
            bf16x8 a1 = *reinterpret_cast<const bf16x8*>(hp + o + 32);
            #pragma unroll
            for (int g=0; g<4; ++g){
              const int ad0 = (((g*16 + c15)*2048) + (c*2+0)*64 + qq*16) ^ lswz;
              const int ad1 = (((g*16 + c15)*2048) + (c*2+1)*64 + qq*16) ^ lswz;
              xc[mt][g] = __builtin_amdgcn_mfma_f32_16x16x32_bf16(
                  a0, *reinterpret_cast<const bf16x8*>((const char*)Wlds + ad0), xc[mt][g], 0,0,0);
              xc[mt][g] = __builtin_amdgcn_mfma_f32_16x16x32_bf16(
                  a1, *reinterpret_cast<const bf16x8*>((const char*)Wlds + ad1), xc[mt][g], 0,0,0);
            }
          }
        }
      }
      // cell epilogue: D row = rb0 + mt*16 + qq*4 + e, col = c15
      #pragma unroll
      for (int mt=0; mt<2; ++mt){
        #pragma unroll
        for (int e=0; e<4; ++e){
          const int r = rb0 + mt*16 + qq*4 + e;
          int i, j; bool act;
          posmap(pass, r, k, L, i, j, act);
          if (act){
            float gi = xc[mt][0][e] + bsI;
            float gf = xc[mt][1][e] + bsF;
            float gg = xc[mt][2][e] + bsG;
            float go = xc[mt][3][e] + bsO;
            float ii = 1.f/(1.f + expf(-gi));
            float ff = 1.f/(1.f + expf(-gf));
            float gt = tanhf(gg);
            float oo = 1.f/(1.f + expf(-go));
            float cn = ff*creg[mt][e] + ii*gt;
            creg[mt][e] = cn;
            float hv = oo*tanhf(cn);
            H[(((size_t)((k & 1) ^ 1)*4 + pass)*512 + b*64 + r)*512 + u]
                = __float2bfloat16(hv);
          }
        }
      }
    }

    // ---- release(k): per-wave, release-ordered (drains vmcnt) ----
    if (lane == 0)
      __hip_atomic_fetch_add(&flag[k], 1, __ATOMIC_RELEASE,
                             __HIP_MEMORY_SCOPE_AGENT);

    // ---- x-GEMM for step k+1 (overlaps other waves' tails / our wait) ----
    if (k < 63){
      xgemm(k+1, xn);
      #pragma unroll
      for (int mt=0; mt<2; ++mt)
        #pragma unroll
        for (int g=0; g<4; ++g) xc[mt][g] = xn[mt][g];
    }
  }

  // epilogue: final projection for step 63
  while (__hip_atomic_load(&flag[63], __ATOMIC_ACQUIRE,
                           __HIP_MEMORY_SCOPE_AGENT) < 128)
    __builtin_amdgcn_s_sleep(2);
  project(63);
}

// labeled[b,i,j] = logsumexp_t of masked pt
__global__ void k_lse(const float* __restrict__ pt_acc, const float* __restrict__ btv,
                      const int* __restrict__ lens, float* __restrict__ lab){
  const int idx = blockIdx.x*256 + threadIdx.x;  // 32768
  const int b = idx >> 12, ij = idx & 4095;
  const int i = ij >> 6, j = ij & 63;
  const int L = lens[b];
  float vs[Tc]; float m = -INFINITY;
  #pragma unroll
  for (int t=0;t<Tc;t++){ vs[t] = pt_val(pt_acc, btv, b, t, i, j, L); m = fmaxf(m, vs[t]); }
  float ssum = 0.f;
  #pragma unroll
  for (int t=0;t<Tc;t++) ssum += expf(vs[t]-m);
  lab[idx] = m + logf(ssum);
}

// matrix-tree slogdet per batch; no-pivot LU (leading minors positive), double.
__global__ __launch_bounds__(256) void k_logz(
    const float* __restrict__ lab, const int* __restrict__ lens,
    float* __restrict__ out)
{
  __shared__ double Md[64][65];
  __shared__ double part[4][64];
  __shared__ double rootv[64];
  const int b = blockIdx.x;
  const int L = lens[b];
  const int tid = threadIdx.x;
  const int c  = tid & 63;
  const int rg = tid >> 6;

  for (int r = rg; r < 64; r += 4){
    float lv = lab[((size_t)b*Sc + r)*Sc + c];
    double a;
    if (r == c) a = 0.0;
    else { a = 1e-5; if (r < L && c < L) a += exp((double)lv); }
    Md[r][c] = a;
  }
  if (rg == 0) rootv[c] = (c < L) ? exp((double)lab[((size_t)b*Sc + c)*Sc + c]) : 0.0;
  __syncthreads();
  {
    double ps = 0.0;
    for (int r = rg; r < 64; r += 4) ps += Md[r][c];
    part[rg][c] = ps;
  }
  __syncthreads();
  const double cs = part[0][c] + part[1][c] + part[2][c] + part[3][c];
  for (int r = rg; r < 64; r += 4){
    double v;
    if (r == 0) v = rootv[c];
    else { v = -Md[r][c]; if (r == c) v += cs + ((c >= L) ? 1.0 : 0.0); }
    Md[r][c] = v;
  }
  __syncthreads();

  double logdet = 0.0;
  for (int p = 0; p < 64; ++p){
    const double diag = Md[p][p];
    logdet += log(fabs(diag));
    if (c > p){
      const double inv = 1.0/diag;
      const double mpc = Md[p][c];
      for (int r = p + 1 + rg; r < 64; r += 4)
        Md[r][c] -= Md[r][p]*inv*mpc;
    }
    __syncthreads();
  }
  if (tid == 0) out[(size_t)Bc*Tc*65*65 + b] = (float)logdet;
}

// pe = _expand_matrix(masked pt)
__global__ void k_out(const float* __restrict__ pt_acc, const float* __restrict__ btv,
                      const int* __restrict__ lens, float* __restrict__ out){
  const int idx = blockIdx.x*256 + threadIdx.x;
  if (idx >= Bc*Tc*65*65) return;
  const int cc = idx % 65; int tmp = idx / 65;
  const int rr = tmp % 65; tmp /= 65;
  const int t  = tmp % Tc; const int b = tmp / Tc;
  float v;
  if (rr == cc) v = 0.f;
  else if (cc == 0) v = NEGF;
  else {
    const int i = (rr == 0) ? (cc-1) : (rr-1);
    v = pt_val(pt_acc, btv, b, t, i, cc-1, lens[b]);
  }
  out[idx] = v;
}

__global__ void k_zero_out(float* out, int n){
  int i = blockIdx.x*256 + threadIdx.x;
  if (i < n) out[i] = 0.f;
}

// ---------------------------------------------------------------------------
extern "C" void kernel_launch(void* const* d_in, const int* in_sizes, int n_in,
                              void* d_out, int out_size, void* d_ws, size_t ws_size,
                              hipStream_t stream)
{
  (void)in_sizes; (void)n_in;
  const int*   lens  = (const int*)  d_in[2];
  const float* sv    = (const float*)d_in[3];
  const float* Wih_f = (const float*)d_in[5];
  const float* Whh_f = (const float*)d_in[6];
  const float* bih_f = (const float*)d_in[7];
  const float* bhh_f = (const float*)d_in[8];
  const float* Wih_b = (const float*)d_in[9];
  const float* Whh_b = (const float*)d_in[10];
  const float* bih_b = (const float*)d_in[11];
  const float* bhh_b = (const float*)d_in[12];
  const float* Wt    = (const float*)d_in[13];
  const float* btv   = (const float*)d_in[14];

  const size_t SVB  = (size_t)Bc*TRIc*Hc*2;       // 17.0 MB bf16
  const size_t WPB  = (size_t)2*32*64*1024*2;     // 8.39 MB bf16
  const size_t PT4  = (size_t)4*PTN*4;            // 8.92 MB (4 parts)
  const size_t HB   = (size_t)2*4*512*512*2;      // 4.19 MB bf16
  const size_t LAB  = (size_t)Bc*Sc*Sc*4;         // 131 KB
  const size_t CNT  = 4096;                       // 8 grp x 2 ph x 64 steps
  const size_t NEED = SVB + WPB + PT4 + HB + LAB + CNT + 8192;

  if (ws_size < NEED) {
    k_zero_out<<<dim3((out_size+255)/256), 256, 0, stream>>>((float*)d_out, out_size);
    return;
  }

  char* base = (char*)d_ws;
  size_t off = 0;
  auto take = [&](size_t bytes)->char*{
    char* r = base + off; off += (bytes + 255) & ~(size_t)255; return r; };

  __hip_bfloat16* svb = (__hip_bfloat16*)take(SVB);
  __hip_bfloat16* Wp  = (__hip_bfloat16*)take(WPB);
  float* pt_acc = (float*)take(PT4);
  __hip_bfloat16* H = (__hip_bfloat16*)take(HB);
  float* lab = (float*)take(LAB);
  int*   cnt = (int*)take(CNT);

  // zero pt parts + H + lab + cnt (contiguous takes)
  (void)hipMemsetAsync(pt_acc, 0, PT4 + HB + LAB + CNT, stream);

  k_cvt <<<dim3(8320), 256, 0, stream>>>(sv, svb, 2129920);
  k_pack<<<dim3(4096), 256, 0, stream>>>(Whh_f, Wih_f, Whh_b, Wih_b, Wp);

  k_persist3<<<dim3(256), 512, 0, stream>>>(Wp, bih_f, bhh_f, bih_b, bhh_b,
                                            svb, Wt, lens, H, pt_acc, cnt);

  k_lse <<<dim3(128), 256, 0, stream>>>(pt_acc, btv, lens, lab);
  k_logz<<<dim3(Bc), 256, 0, stream>>>(lab, lens, (float*)d_out);
  k_out <<<dim3((Bc*Tc*65*65 + 255)/256), 256, 0, stream>>>(pt_acc, btv, lens, (float*)d_out);
}

// Round 11
// 1460.480 us; speedup vs baseline: 47.6343x; 47.6343x over previous
//
#include <hip/hip_runtime.h>
#include <hip/hip_bf16.h>
#include <math.h>

#define NEGF (-1000000000.0f)

constexpr int Bc = 8;
constexpr int Sc = 64;
constexpr int Hc = 512;
constexpr int Tc = 17;
constexpr int TRIc = Sc*(Sc+1)/2;     // 2080
constexpr int PTN  = Bc*Tc*Sc*Sc;     // elements per pt part

typedef __bf16 bf16x8 __attribute__((ext_vector_type(8)));
typedef float  f32x4  __attribute__((ext_vector_type(4)));

__device__ __forceinline__ int tri_idx(int i, int j){
  return i*Sc - (i*(i-1))/2 + (j - i);
}

// L1-bypassing 16B read of H (2 x 8B relaxed agent atomic loads -> sc0).
// Needed because H parity buffers are re-read every 2 steps and written by
// OTHER CUs; relaxed atomics read the XCD-shared L2 directly, no fences.
__device__ __forceinline__ bf16x8 hload8(const __hip_bfloat16* p){
  union { unsigned long long q[2]; bf16x8 v; } u;
  const unsigned long long* s = (const unsigned long long*)p;
  u.q[0] = __hip_atomic_load(s,     __ATOMIC_RELAXED, __HIP_MEMORY_SCOPE_AGENT);
  u.q[1] = __hip_atomic_load(s + 1, __ATOMIC_RELAXED, __HIP_MEMORY_SCOPE_AGENT);
  return u.v;
}

// (i,j) position + activity for (pass, row r, step k, length L)
__device__ __forceinline__ void posmap(int pass, int r, int k, int L,
                                       int& i, int& j, bool& act){
  if      (pass == 0){ act = (r < L - k);            i = r;     j = L - 1 - k; }
  else if (pass == 1){ act = (r < L - k);            i = r;     j = r + k;     }
  else if (pass == 2){ act = (r >= k) && (r < L);    i = r - k; j = r;         }
  else               { act = (r >= k) && (r < L);    i = k;     j = r;         }
  if (!act){ i = 0; j = 0; }
}

// masked pt value; pt split in 4 parts of PTN elements
__device__ __forceinline__ float pt_val(const float* __restrict__ pt_acc,
                                        const float* __restrict__ btv,
                                        int b, int t, int i, int j, int L){
  const bool masked = (i > j) || (j >= L) ||
                      (t < Tc-1 && i == j) || (t == Tc-1 && i < j);
  if (masked) return NEGF;
  const size_t idx = (((size_t)b*Tc + t)*Sc + i)*Sc + j;
  return pt_acc[idx] + pt_acc[PTN + idx] + pt_acc[2*PTN + idx]
       + pt_acc[3*PTN + idx] + btv[t];
}

// ---------------------------------------------------------------------------
__global__ __launch_bounds__(256) void k_cvt(const float* __restrict__ s,
                                             __hip_bfloat16* __restrict__ d, int n4){
  int i = blockIdx.x*256 + threadIdx.x;
  if (i >= n4) return;
  float4 v = reinterpret_cast<const float4*>(s)[i];
  union { __hip_bfloat16 h[4]; ushort4 u; } p;
  p.h[0] = __float2bfloat16(v.x); p.h[1] = __float2bfloat16(v.y);
  p.h[2] = __float2bfloat16(v.z); p.h[3] = __float2bfloat16(v.w);
  reinterpret_cast<ushort4*>(d)[i] = p.u;
}

// ---------------------------------------------------------------------------
// Weight prepack: Wp[wset][us(32)][row(64)][k(1024)] bf16
// ---------------------------------------------------------------------------
__global__ __launch_bounds__(256) void k_pack(
    const float* __restrict__ Whh_f, const float* __restrict__ Wih_f,
    const float* __restrict__ Whh_b, const float* __restrict__ Wih_b,
    __hip_bfloat16* __restrict__ Wp)
{
  int idx = blockIdx.x*256 + threadIdx.x;   // 1,048,576 quads
  int k4  = idx & 255;
  int row = (idx >> 8) & 63;
  int us  = (idx >> 14) & 31;
  int ws  = idx >> 19;
  int g = row >> 4, uu = row & 15;
  int srow = g*512 + us*16 + uu;
  int k = k4*4;
  const float* src;
  if (ws == 0) src = (k < 512) ? Whh_f : Wih_f;
  else         src = (k < 512) ? Whh_b : Wih_b;
  float4 v = *reinterpret_cast<const float4*>(src + (size_t)srow*512 + (k & 511));
  union { __hip_bfloat16 h[4]; ushort4 u; } p;
  p.h[0] = __float2bfloat16(v.x); p.h[1] = __float2bfloat16(v.y);
  p.h[2] = __float2bfloat16(v.z); p.h[3] = __float2bfloat16(v.w);
  *reinterpret_cast<ushort4*>(Wp + (size_t)idx*4) = p.u;
}

// ---------------------------------------------------------------------------
// Persistent 4-pass LSTM. 256 blocks x 512 threads, 1 block/CU (128 KiB LDS).
// grp = bid&7 (XCD-pinned: pp = grp>>2 weight set, bq = grp&3 batch pair);
// us = bid>>3. All cross-block traffic INTRA-XCD. Flags RELAXED (no cache
// maintenance); __syncthreads drains vmcnt before the t0 post (stores in L2);
// H reads bypass L1 via hload8.
// ---------------------------------------------------------------------------
__global__ __launch_bounds__(512) void k_persist(
    const __hip_bfloat16* __restrict__ Wp,
    const float* __restrict__ bih_f, const float* __restrict__ bhh_f,
    const float* __restrict__ bih_b, const float* __restrict__ bhh_b,
    const __hip_bfloat16* __restrict__ svb, const float* __restrict__ Wt,
    const int* __restrict__ lens,
    __hip_bfloat16* __restrict__ H,
    float* __restrict__ pt_acc, int* __restrict__ cnt)
{
  const int bid = blockIdx.x;
  const int grp = bid & 7;          // XCD-aligned group
  const int us  = bid >> 3;         // 0..31
  const int pp  = grp >> 2;         // weight set (one per XCD)
  const int bq  = grp & 3;          // batch pair (one per XCD)
  const int L0 = lens[bq*2], L1 = lens[bq*2+1];

  const float* b1 = pp ? bih_b : bih_f;
  const float* b2 = pp ? bhh_b : bhh_f;

  const int t = threadIdx.x, lane = t & 63, wv = t >> 6;
  const int c15 = lane & 15, qq = lane >> 4;
  const int ph = wv >> 2;           // pass half
  const int mq = wv & 3;            // row quarter
  const int pass = pp ? (ph ? 2 : 1) : (ph ? 3 : 0);
  const int b_loc = mq >> 1;
  const int b  = bq*2 + b_loc;
  const int L  = b_loc ? L1 : L0;
  const int rb0 = (mq & 1)*32;      // within-batch row base (+mt*16)

  __shared__ ushort Wlds[65536];    // 128 KiB: 64 rows x 2048 B, XOR-swizzled

  // ---- one-time W stage (swizzle byte-addr ^ (row&7)<<4) ----
  {
    const __hip_bfloat16* Wpb = Wp + (((size_t)pp*32 + us)*64)*1024;
    const int row = t >> 3, c8 = t & 7;
    const int swz = (row & 7) << 4;
    #pragma unroll
    for (int q=0; q<16; ++q){
      int4 v = *reinterpret_cast<const int4*>(Wpb + (size_t)row*1024 + c8*128 + q*8);
      *reinterpret_cast<int4*>((char*)Wlds + ((row*2048 + c8*256 + q*16) ^ swz)) = v;
    }
  }

  const int u = us*16 + c15;
  const float bsI = b1[u]        + b2[u];
  const float bsF = b1[512 + u]  + b2[512 + u];
  const float bsG = b1[1024 + u] + b2[1024 + u];
  const float bsO = b1[1536 + u] + b2[1536 + u];
  const int lswz = (c15 & 7) << 4;

  // projection: pidx = us*4 + mq in 0..127 per pass-half (bijective over grp)
  const int pidx = us*4 + mq;
  const int bp   = bq*2 + (pidx >> 6);
  const int rp   = pidx & 63;
  const int Lp   = (pidx >> 6) ? L1 : L0;
  const int off_wtp = (pass==0 || pass==2) ? 512 : 0;

  float creg[2][4];
  #pragma unroll
  for (int mt=0; mt<2; ++mt)
    #pragma unroll
    for (int e=0; e<4; ++e) creg[mt][e] = 0.f;

  __syncthreads();                  // Wlds ready

  for (int k=0; k<64; ++k){
    const int cur = k & 1;

    bool act_t[2];
    #pragma unroll
    for (int mt=0; mt<2; ++mt){
      const int rbase = rb0 + mt*16;
      act_t[mt] = (pass < 2) ? (rbase < L - k)
                             : (rbase + 15 >= k && rbase < L);
    }

    if (act_t[0] || act_t[1]){
      const __hip_bfloat16* hp[2];
      const __hip_bfloat16* xp[2];
      #pragma unroll
      for (int mt=0; mt<2; ++mt){
        const int r = rb0 + mt*16 + c15;
        int i, j; bool a_;
        posmap(pass, r, k, L, i, j, a_);
        hp[mt] = H + (((size_t)cur*4 + pass)*512 + b*64 + r)*512;
        xp[mt] = svb + ((size_t)b*TRIc + tri_idx(i, j))*512;
      }

      f32x4 acc[2][4];
      #pragma unroll
      for (int mt=0; mt<2; ++mt)
        #pragma unroll
        for (int g=0; g<4; ++g) acc[mt][g] = f32x4{0.f,0.f,0.f,0.f};

      #pragma unroll 4
      for (int c=0; c<16; ++c){
        bf16x8 a[2][2];               // [kk][mt]
        const int o = (c & 7)*64 + qq*8;
        #pragma unroll
        for (int mt=0; mt<2; ++mt){
          if (c < 8){
            a[0][mt] = hload8(hp[mt] + o);
            a[1][mt] = hload8(hp[mt] + o + 32);
          } else {
            a[0][mt] = *reinterpret_cast<const bf16x8*>(xp[mt] + o);
            a[1][mt] = *reinterpret_cast<const bf16x8*>(xp[mt] + o + 32);
          }
        }
        #pragma unroll
        for (int kk=0; kk<2; ++kk){
          #pragma unroll
          for (int g=0; g<4; ++g){
            const int addr = (((g*16 + c15)*2048) + (c*2 + kk)*64 + qq*16) ^ lswz;
            bf16x8 bf = *reinterpret_cast<const bf16x8*>((const char*)Wlds + addr);
            acc[0][g] = __builtin_amdgcn_mfma_f32_16x16x32_bf16(a[kk][0], bf, acc[0][g], 0,0,0);
            acc[1][g] = __builtin_amdgcn_mfma_f32_16x16x32_bf16(a[kk][1], bf, acc[1][g], 0,0,0);
          }
        }
      }

      // cell epilogue: D row = rb0 + mt*16 + qq*4 + e, col = c15
      #pragma unroll
      for (int mt=0; mt<2; ++mt){
        #pragma unroll
        for (int e=0; e<4; ++e){
          const int r = rb0 + mt*16 + qq*4 + e;
          int i, j; bool act;
          posmap(pass, r, k, L, i, j, act);
          if (act){
            float gi = acc[mt][0][e] + bsI;
            float gf = acc[mt][1][e] + bsF;
            float gg = acc[mt][2][e] + bsG;
            float go = acc[mt][3][e] + bsO;
            float ii = 1.f/(1.f + expf(-gi));
            float ff = 1.f/(1.f + expf(-gf));
            float gt = tanhf(gg);
            float oo = 1.f/(1.f + expf(-go));
            float cn = ff*creg[mt][e] + ii*gt;
            creg[mt][e] = cn;
            float hv = oo*tanhf(cn);
            H[(((size_t)(cur^1)*4 + pass)*512 + b*64 + r)*512 + u] = __float2bfloat16(hv);
          }
        }
      }
    }

    // ---- group sync (32 blocks, one XCD). __syncthreads drains vmcnt, so
    // all H stores of this block are in the shared L2 before t0 posts.
    // RELAXED atomics: no L2 writeback/invalidate (the R6-R10 killer).
    __syncthreads();
    if (t == 0){
      __hip_atomic_fetch_add(&cnt[grp*64 + k], 1, __ATOMIC_RELAXED, __HIP_MEMORY_SCOPE_AGENT);
      while (__hip_atomic_load(&cnt[grp*64 + k], __ATOMIC_RELAXED, __HIP_MEMORY_SCOPE_AGENT) < 32)
        __builtin_amdgcn_s_sleep(1);
    }
    __syncthreads();

    // ---- fused projection for step k (h complete in parity cur^1) ----
    if (k < Lp){
      int pi, pj; bool pact;
      posmap(pass, rp, k, Lp, pi, pj, pact);
      if (pact){
        const __hip_bfloat16* hrow =
            H + (((size_t)(cur^1)*4 + pass)*512 + bp*64 + rp)*512;
        bf16x8 hv8 = hload8(hrow + lane*8);
        float hf[8];
        #pragma unroll
        for (int e=0; e<8; ++e) hf[e] = (float)hv8[e];
        float part[Tc];
        #pragma unroll
        for (int tt=0; tt<Tc; ++tt){
          const float* w = Wt + (size_t)tt*1024 + off_wtp + lane*8;
          float4 w0 = *reinterpret_cast<const float4*>(w);
          float4 w1 = *reinterpret_cast<const float4*>(w + 4);
          part[tt] = hf[0]*w0.x + hf[1]*w0.y + hf[2]*w0.z + hf[3]*w0.w
                   + hf[4]*w1.x + hf[5]*w1.y + hf[6]*w1.z + hf[7]*w1.w;
        }
        float* ptp = pt_acc + (size_t)(us & 3)*PTN;
        #pragma unroll
        for (int tt=0; tt<Tc; ++tt){
          float s = part[tt];
          s += __shfl_xor(s, 1);  s += __shfl_xor(s, 2);  s += __shfl_xor(s, 4);
          s += __shfl_xor(s, 8);  s += __shfl_xor(s, 16); s += __shfl_xor(s, 32);
          if (lane == tt)
            atomicAdd(&ptp[(((size_t)bp*Tc + tt)*Sc + pi)*Sc + pj], s);
        }
      }
    }
  }
}

// labeled[b,i,j] = logsumexp_t of masked pt
__global__ void k_lse(const float* __restrict__ pt_acc, const float* __restrict__ btv,
                      const int* __restrict__ lens, float* __restrict__ lab){
  const int idx = blockIdx.x*256 + threadIdx.x;  // 32768
  const int b = idx >> 12, ij = idx & 4095;
  const int i = ij >> 6, j = ij & 63;
  const int L = lens[b];
  float vs[Tc]; float m = -INFINITY;
  #pragma unroll
  for (int t=0;t<Tc;t++){ vs[t] = pt_val(pt_acc, btv, b, t, i, j, L); m = fmaxf(m, vs[t]); }
  float ssum = 0.f;
  #pragma unroll
  for (int t=0;t<Tc;t++) ssum += expf(vs[t]-m);
  lab[idx] = m + logf(ssum);
}

// matrix-tree slogdet per batch; no-pivot LU (leading minors positive), double.
__global__ __launch_bounds__(256) void k_logz(
    const float* __restrict__ lab, const int* __restrict__ lens,
    float* __restrict__ out)
{
  __shared__ double Md[64][65];
  __shared__ double part[4][64];
  __shared__ double rootv[64];
  const int b = blockIdx.x;
  const int L = lens[b];
  const int tid = threadIdx.x;
  const int c  = tid & 63;
  const int rg = tid >> 6;

  for (int r = rg; r < 64; r += 4){
    float lv = lab[((size_t)b*Sc + r)*Sc + c];
    double a;
    if (r == c) a = 0.0;
    else { a = 1e-5; if (r < L && c < L) a += exp((double)lv); }
    Md[r][c] = a;
  }
  if (rg == 0) rootv[c] = (c < L) ? exp((double)lab[((size_t)b*Sc + c)*Sc + c]) : 0.0;
  __syncthreads();
  {
    double ps = 0.0;
    for (int r = rg; r < 64; r += 4) ps += Md[r][c];
    part[rg][c] = ps;
  }
  __syncthreads();
  const double cs = part[0][c] + part[1][c] + part[2][c] + part[3][c];
  for (int r = rg; r < 64; r += 4){
    double v;
    if (r == 0) v = rootv[c];
    else { v = -Md[r][c]; if (r == c) v += cs + ((c >= L) ? 1.0 : 0.0); }
    Md[r][c] = v;
  }
  __syncthreads();

  double logdet = 0.0;
  for (int p = 0; p < 64; ++p){
    const double diag = Md[p][p];
    logdet += log(fabs(diag));
    if (c > p){
      const double inv = 1.0/diag;
      const double mpc = Md[p][c];
      for (int r = p + 1 + rg; r < 64; r += 4)
        Md[r][c] -= Md[r][p]*inv*mpc;
    }
    __syncthreads();
  }
  if (tid == 0) out[(size_t)Bc*Tc*65*65 + b] = (float)logdet;
}

// pe = _expand_matrix(masked pt)
__global__ void k_out(const float* __restrict__ pt_acc, const float* __restrict__ btv,
                      const int* __restrict__ lens, float* __restrict__ out){
  const int idx = blockIdx.x*256 + threadIdx.x;
  if (idx >= Bc*Tc*65*65) return;
  const int cc = idx % 65; int tmp = idx / 65;
  const int rr = tmp % 65; tmp /= 65;
  const int t  = tmp % Tc; const int b = tmp / Tc;
  float v;
  if (rr == cc) v = 0.f;
  else if (cc == 0) v = NEGF;
  else {
    const int i = (rr == 0) ? (cc-1) : (rr-1);
    v = pt_val(pt_acc, btv, b, t, i, cc-1, lens[b]);
  }
  out[idx] = v;
}

__global__ void k_zero_out(float* out, int n){
  int i = blockIdx.x*256 + threadIdx.x;
  if (i < n) out[i] = 0.f;
}

// ---------------------------------------------------------------------------
extern "C" void kernel_launch(void* const* d_in, const int* in_sizes, int n_in,
                              void* d_out, int out_size, void* d_ws, size_t ws_size,
                              hipStream_t stream)
{
  (void)in_sizes; (void)n_in;
  const int*   lens  = (const int*)  d_in[2];
  const float* sv    = (const float*)d_in[3];
  const float* Wih_f = (const float*)d_in[5];
  const float* Whh_f = (const float*)d_in[6];
  const float* bih_f = (const float*)d_in[7];
  const float* bhh_f = (const float*)d_in[8];
  const float* Wih_b = (const float*)d_in[9];
  const float* Whh_b = (const float*)d_in[10];
  const float* bih_b = (const float*)d_in[11];
  const float* bhh_b = (const float*)d_in[12];
  const float* Wt    = (const float*)d_in[13];
  const float* btv   = (const float*)d_in[14];

  const size_t SVB  = (size_t)Bc*TRIc*Hc*2;       // 17.0 MB bf16
  const size_t WPB  = (size_t)2*32*64*1024*2;     // 8.39 MB bf16
  const size_t PT4  = (size_t)4*PTN*4;            // 8.92 MB (4 parts)
  const size_t HB   = (size_t)2*4*512*512*2;      // 4.19 MB bf16
  const size_t LAB  = (size_t)Bc*Sc*Sc*4;         // 131 KB
  const size_t CNT  = 2048;                       // 8 groups x 64 steps
  const size_t NEED = SVB + WPB + PT4 + HB + LAB + CNT + 8192;

  if (ws_size < NEED) {
    k_zero_out<<<dim3((out_size+255)/256), 256, 0, stream>>>((float*)d_out, out_size);
    return;
  }

  char* base = (char*)d_ws;
  size_t off = 0;
  auto take = [&](size_t bytes)->char*{
    char* r = base + off; off += (bytes + 255) & ~(size_t)255; return r; };

  __hip_bfloat16* svb = (__hip_bfloat16*)take(SVB);
  __hip_bfloat16* Wp  = (__hip_bfloat16*)take(WPB);
  float* pt_acc = (float*)take(PT4);
  __hip_bfloat16* H = (__hip_bfloat16*)take(HB);
  float* lab = (float*)take(LAB);
  int*   cnt = (int*)take(CNT);

  // zero pt parts + H + lab + cnt (contiguous takes)
  (void)hipMemsetAsync(pt_acc, 0, PT4 + HB + LAB + CNT, stream);

  k_cvt <<<dim3(8320), 256, 0, stream>>>(sv, svb, 2129920);
  k_pack<<<dim3(4096), 256, 0, stream>>>(Whh_f, Wih_f, Whh_b, Wih_b, Wp);

  k_persist<<<dim3(256), 512, 0, stream>>>(Wp, bih_f, bhh_f, bih_b, bhh_b,
                                           svb, Wt, lens, H, pt_acc, cnt);

  k_lse <<<dim3(128), 256, 0, stream>>>(pt_acc, btv, lens, lab);
  k_logz<<<dim3(Bc), 256, 0, stream>>>(lab, lens, (float*)d_out);
  k_out <<<dim3((Bc*Tc*65*65 + 255)/256), 256, 0, stream>>>(pt_acc, btv, lens, (float*)d_out);
}